// Round 1
// 704.777 us; speedup vs baseline: 1.1317x; 1.1317x over previous
//
#include <hip/hip_runtime.h>
#include <hip/hip_fp16.h>
#include <cstdint>

#define DEV static __device__ __forceinline__

typedef _Float16 h2v __attribute__((ext_vector_type(2)));
typedef _Float16 half8 __attribute__((ext_vector_type(8)));
typedef float float4v __attribute__((ext_vector_type(4)));

union U32H2 { uint32_t u; _Float16 f[2]; };

DEV uint32_t pack_f2(float a, float b) {
    auto p = __builtin_amdgcn_cvt_pkrtz(a, b);
    return __builtin_bit_cast(uint32_t, p);
}

DEV half8 bc8(uint4 v) { return __builtin_bit_cast(half8, v); }

DEV float sigmoidf_(float x) { return 1.0f / (1.0f + __expf(-x)); }

DEV void gl_lds16(const void* gsrc, void* ldst) {
    __builtin_amdgcn_global_load_lds(
        (const __attribute__((address_space(1))) uint32_t*)gsrc,
        (__attribute__((address_space(3))) uint32_t*)ldst, 16, 0, 0);
}

// select element r (0..3) of (bsel ? hi : lo) with compile-time-constant indices only
DEV float pick4(float4v lo, float4v hi, int bsel, int r) {
    float v0 = bsel ? hi[0] : lo[0];
    float v1 = bsel ? hi[1] : lo[1];
    float v2 = bsel ? hi[2] : lo[2];
    float v3 = bsel ? hi[3] : lo[3];
    float x01 = (r & 1) ? v1 : v0;
    float x23 = (r & 1) ? v3 : v2;
    return (r & 2) ? x23 : x01;
}

// ---------------- workspace layout (uint32 units) ----------------
// N=384 H=256 Z=128 ED=128 AH=64
static const size_t OFF_W16T  = 0;          // 98304  : Whh f16 as MFMA A-fragments (k_gru layout)
static const size_t OFF_GI    = 98304;      // 768    : gsum = gi + bhh (r,z thirds), gi only (n third)
static const size_t OFF_CC    = 99072;      // 128
static const size_t OFF_BF    = 99200;      // 65536  : W2A in MFMA B-frag layout
static const size_t OFF_NODES = 164736;     // 98304  : GRU outputs fp32 [384][256]
static const size_t OFF_PF    = 263040;     // 196608 : P in MFMA A-frag layout
static const size_t OFF_QF    = 459648;     // 196608 : Q natural f16 [384][512 u32]
static const size_t OFF_R0    = 656256;     // 24576
static const size_t OFF_R1    = 680832;     // 24576
static const size_t OFF_TT    = 705408;     // 9437184: T f16 [s][d][64 u32]
static const size_t OFF_ATT0  = 10142592;   // 147456
static const size_t OFF_ATT1  = 10290048;   // 147456
static const size_t OFF_AGG   = 10437504;   // 98304
static const size_t OFF_X0    = 10535808;   // 98304
static const size_t OFF_CS    = 10634112;   // 384
static const size_t OFF_V     = 10634496;   // 256
static const size_t WS_TOTAL  = 10634752;   // u32 elems (~42.5 MB)

// ---------------- prep kernels ----------------
// WL: Whh as MFMA 16x16x32 A-fragments, GATE-LOCAL row order.
// Wave wv owns h-elements [wv*32, wv*32+32). Its 6 row-tiles rt map to
// original Whh row = (rt>>1)*256 + wv*32 + ((rt&1)<<4) + (lane&15).
// uint4 index o4 = c*512 + t (c = rt*8+kt, t = tid).
__global__ void k_prep_w16(const float* __restrict__ Whh, uint32_t* __restrict__ WL) {
    int o4 = blockIdx.x * 256 + threadIdx.x;           // < 24576
    int c = o4 >> 9, t = o4 & 511;
    int rt = c >> 3, kt = c & 7;
    int lane = t & 63, wv = t >> 6;
    int row = (rt >> 1) * 256 + wv * 32 + ((rt & 1) << 4) + (lane & 15);
    int k0 = kt*32 + (lane >> 4)*8;
    const float* src = Whh + row*256 + k0;
    uint4 o;
    o.x = pack_f2(src[0], src[1]);
    o.y = pack_f2(src[2], src[3]);
    o.z = pack_f2(src[4], src[5]);
    o.w = pack_f2(src[6], src[7]);
    ((uint4*)WL)[o4] = o;
}

// gsum: thirds {gir+bhr, giz+bhz, gin}. (bhh_n must stay separate: n-gate is
// tanh(gin + r*(Whh_n h + bhh_n)), so bhh_n is scaled by r.)
__global__ void k_prep_gi(const float* __restrict__ z, const float* __restrict__ Wih,
                          const float* __restrict__ bih, const float* __restrict__ bhh,
                          float* __restrict__ gs) {
    int o = blockIdx.x * 256 + threadIdx.x;            // < 768
    float acc = bih[o];
    if (o < 512) acc += bhh[o];
    for (int i = 0; i < 128; ++i) acc += Wih[o*128 + i] * z[i];
    gs[o] = acc;
}

__global__ void k_prep_cc(const float* __restrict__ eg_b2, const float* __restrict__ a0W1,
                          const float* __restrict__ a1W1, float* __restrict__ cc) {
    int t = threadIdx.x;                               // < 128
    const float* A = (t < 64) ? a0W1 : a1W1;
    int j = t & 63;
    float acc = 0.f;
    for (int i = 0; i < 128; ++i) acc += eg_b2[i] * A[i*64 + j];
    cc[t] = acc;
}

// W2A[k][n] in MFMA B-frag layout
__global__ void k_prep_w2a(const float* __restrict__ eg_W2, const float* __restrict__ a0W1,
                           const float* __restrict__ a1W1, uint32_t* __restrict__ BF) {
    int idx = blockIdx.x * 256 + threadIdx.x;          // < 65536
    int k2 = idx >> 7, n = idx & 127;
    const float* A = (n < 64) ? (a0W1 + n) : (a1W1 + (n - 64));
    const float* w0 = eg_W2 + (2*k2) * 128;
    float a = 0.f, b = 0.f;
    for (int i = 0; i < 128; ++i) {
        float av = A[i*64];
        a += w0[i] * av;
        b += w0[128 + i] * av;
    }
    int kk = k2 >> 4, jgrp = (k2 >> 2) & 3, sub = k2 & 3;
    int lane = jgrp*16 + (n & 15), t = n >> 4;
    BF[((kk*8 + t)*64 + lane)*4 + sub] = pack_f2(a, b);
}

// ---------------- GRU: 512 threads; Whh in AGPRs as MFMA A-operands ----------------
// v3: gate-local rows -> every wave self-contained for its 32 h-elements.
// B is h broadcast to all 16 cols => D identical in every column => every lane
// holds the full D fragments; lanes (c = lane&15) < 8 each own one h-element
// (r = c&3, bsel = c>>2, i = kq*4 + r + 16*bsel) and compute its gate update
// in-register. One raw s_barrier per step (lgkm-only drain: the nodes[] HBM
// store never blocks), h double-buffered in LDS to remove the RAW/WAR hazard.
__global__ void __launch_bounds__(512, 2)
k_gru(const float* __restrict__ gs, const float* __restrict__ bhh,
      const uint32_t* __restrict__ WL, float* __restrict__ nodes) {
    int tid = threadIdx.x;
    int lane = tid & 63, wv = tid >> 6;
    int kq = lane >> 4, c = lane & 15;
    __shared__ __align__(16) _Float16 hh16[512];       // 2 buffers x 256 f16

    // load 48 A-frags, pin each 32-bit component to the AGPR class
    uint4 w[48];
    const uint4* wl4 = (const uint4*)WL;
    #pragma unroll
    for (int cc = 0; cc < 48; ++cc) w[cc] = wl4[cc*512 + tid];
    #pragma unroll
    for (int cc = 0; cc < 48; ++cc)
        asm volatile("" : "+a"(w[cc].x), "+a"(w[cc].y), "+a"(w[cc].z), "+a"(w[cc].w));

    const float L2E = 1.44269504088896f;
    int r = c & 3, bsel = (c >> 2) & 1;                // c>=8 duplicates c-8; inactive
    int i_loc = kq*4 + r + bsel*16;
    int gidx = wv*32 + i_loc;
    float pr = -L2E * gs[gidx];
    float pz = -L2E * gs[256 + gidx];
    float gin_l = gs[512 + gidx];
    float bn_l  = bhh[512 + gidx];
    float pn = -2.f * L2E * gin_l;
    bool active = (c < 8);

    float h = 0.f;
    if (tid < 256) ((uint32_t*)hh16)[tid] = 0u;        // zero both buffers
    __syncthreads();

    const float4v z4 = {0.f, 0.f, 0.f, 0.f};
    int par = 0;
    for (int t = 0; t < 384; ++t) {
        const _Float16* hb = hh16 + par*256 + kq*8;
        uint4 b[8];
        #pragma unroll
        for (int kt = 0; kt < 8; ++kt) b[kt] = *(const uint4*)(hb + kt*32);

        float4v d[6];
        #pragma unroll
        for (int rt = 0; rt < 6; ++rt)
            d[rt] = __builtin_amdgcn_mfma_f32_16x16x32_f16(bc8(w[rt*8]), bc8(b[0]), z4, 0, 0, 0);
        #pragma unroll
        for (int kt = 1; kt < 8; ++kt)
            #pragma unroll
            for (int rt = 0; rt < 6; ++rt)
                d[rt] = __builtin_amdgcn_mfma_f32_16x16x32_f16(bc8(w[rt*8 + kt]), bc8(b[kt]), d[rt], 0, 0, 0);

        // this lane's gh values: gate g lives in tiles {2g, 2g+1}, row r of quad
        float ghr = pick4(d[0], d[1], bsel, r);
        float ghz = pick4(d[2], d[3], bsel, r);
        float ghn = pick4(d[4], d[5], bsel, r);

        float er = __builtin_amdgcn_exp2f(__builtin_fmaf(ghr, -L2E, pr));
        float rg = __builtin_amdgcn_rcpf(1.f + er);
        float eu = __builtin_amdgcn_exp2f(__builtin_fmaf(ghz, -L2E, pz));
        float u  = __builtin_amdgcn_rcpf(1.f + eu);
        float tm = ghn + bn_l;
        float q  = __builtin_fmaf(rg * tm, -2.f * L2E, pn);
        float e2 = __builtin_amdgcn_exp2f(q);
        float nn = __builtin_fmaf(2.f, __builtin_amdgcn_rcpf(1.f + e2), -1.f);
        h = nn + u * (h - nn);

        if (active) {
            hh16[(par ^ 1)*256 + gidx] = (_Float16)h;
            nodes[t*256 + gidx] = h;                   // HBM store: not drained at barrier
        }
        asm volatile("s_waitcnt lgkmcnt(0)" ::: "memory");
        __builtin_amdgcn_sched_barrier(0);
        __builtin_amdgcn_s_barrier();
        __builtin_amdgcn_sched_barrier(0);
        par ^= 1;
    }
}

// ---------------- P (A-frag layout), Q (natural f16), R0 ----------------
__global__ void k_pq(const float* __restrict__ nodes, const float* __restrict__ eg_W1,
                     const float* __restrict__ eg_b1, const float* __restrict__ a0W1,
                     const float* __restrict__ a0b1, const float* __restrict__ cc,
                     uint32_t* __restrict__ PF, uint32_t* __restrict__ QF,
                     float* __restrict__ R0) {
    int tid = threadIdx.x;
    int s0 = blockIdx.x * 4;
    __shared__ float ns[4][256];
    #pragma unroll
    for (int q = 0; q < 4; ++q) ns[q][tid] = nodes[(s0+q)*256 + tid];
    __syncthreads();

    int k0 = tid * 4;
    float acc[4][4];
    #pragma unroll
    for (int q = 0; q < 4; ++q) { acc[q][0]=0;acc[q][1]=0;acc[q][2]=0;acc[q][3]=0; }
    for (int i = 0; i < 256; ++i) {
        float4 wv = *(const float4*)&eg_W1[i*1024 + k0];
        #pragma unroll
        for (int q = 0; q < 4; ++q) {
            float nv = ns[q][i];
            acc[q][0] += nv*wv.x; acc[q][1] += nv*wv.y;
            acc[q][2] += nv*wv.z; acc[q][3] += nv*wv.w;
        }
    }
    float4 bv = *(const float4*)&eg_b1[k0];
    {
        int kk = k0 >> 5;
        int lgrp = ((k0 >> 3) & 3) * 16;
        int sub = (k0 & 7) >> 1;                       // 0 or 2
        #pragma unroll
        for (int q = 0; q < 4; ++q) {
            int s = s0 + q, g = s >> 4, srow = s & 15;
            uint2 pw;
            pw.x = pack_f2(acc[q][0] + bv.x, acc[q][1] + bv.y);
            pw.y = pack_f2(acc[q][2] + bv.z, acc[q][3] + bv.w);
            *(uint2*)(PF + (((g*32 + kk)*64 + lgrp + srow) << 2) + sub) = pw;
        }
    }

    #pragma unroll
    for (int q = 0; q < 4; ++q) { acc[q][0]=0;acc[q][1]=0;acc[q][2]=0;acc[q][3]=0; }
    for (int i = 0; i < 256; ++i) {
        float4 wv = *(const float4*)&eg_W1[(256+i)*1024 + k0];
        #pragma unroll
        for (int q = 0; q < 4; ++q) {
            float nv = ns[q][i];
            acc[q][0] += nv*wv.x; acc[q][1] += nv*wv.y;
            acc[q][2] += nv*wv.z; acc[q][3] += nv*wv.w;
        }
    }
    #pragma unroll
    for (int q = 0; q < 4; ++q) {
        uint2 pw;
        pw.x = pack_f2(acc[q][0], acc[q][1]);
        pw.y = pack_f2(acc[q][2], acc[q][3]);
        ((uint2*)QF)[(s0+q)*256 + tid] = pw;           // QF[d][k/2], natural order
    }

    int srow = tid >> 6, j = tid & 63;
    float racc = a0b1[j] + cc[j];
    for (int i = 0; i < 256; ++i) racc += ns[srow][i] * a0W1[(128+i)*64 + j];
    R0[(s0+srow)*64 + j] = racc;
}

// ---------------- phase A (MFMA): T[s,d,:] = relu(P[s]+Q[d]) @ W2A ----------------
__global__ void __launch_bounds__(256, 2)
k_phaseA_mfma(const uint32_t* __restrict__ PF, const uint32_t* __restrict__ QF,
              const uint32_t* __restrict__ BF, uint32_t* __restrict__ TT) {
    __shared__ __align__(16) char smem[69632];
    uint4* Qs4 = (uint4*)smem;                         // 16 d x 128 uint4 = 32 KB
    uint4* Ps4 = (uint4*)(smem + 32768);               // 4 kk x 64 lane = 4 KB
    uint4* Bs4 = (uint4*)(smem + 36864);               // 4 kk x 8 t x 64 lane = 32 KB

    int tid = threadIdx.x;
    int lane = tid & 63, wv = tid >> 6;
    int g = blockIdx.x, d0 = blockIdx.y * 16;

    {
        const char* src = (const char*)(QF + (size_t)d0 * 512);
        for (int off = wv*1024 + lane*16; off < 32768; off += 4096)
            gl_lds16(src + off, (char*)Qs4 + off);
    }

    float4v acc[4][8];
    #pragma unroll
    for (int t = 0; t < 4; ++t)
        #pragma unroll
        for (int n = 0; n < 8; ++n) acc[t][n] = 0.f;

    for (int c = 0; c < 8; ++c) {
        __syncthreads();
        {
            const char* psrc = (const char*)(PF + (size_t)(g*32 + c*4) * 256);
            for (int off = wv*1024 + lane*16; off < 4096; off += 4096)
                gl_lds16(psrc + off, (char*)Ps4 + off);
            const char* bsrc = (const char*)(BF + (size_t)c * 8192);
            for (int off = wv*1024 + lane*16; off < 32768; off += 4096)
                gl_lds16(bsrc + off, (char*)Bs4 + off);
        }
        __syncthreads();

        #pragma unroll
        for (int kkl = 0; kkl < 4; ++kkl) {
            int kkg = c*4 + kkl;
            half8 b[8];
            #pragma unroll
            for (int n = 0; n < 8; ++n) b[n] = bc8(Bs4[(kkl*8 + n)*64 + lane]);
            half8 p8 = bc8(Ps4[kkl*64 + lane]);
            #pragma unroll
            for (int t = 0; t < 4; ++t) {
                half8 q8 = bc8(Qs4[(wv*4 + t)*128 + kkg*4 + (lane >> 4)]);
                half8 x = p8 + q8;
                half8 z = 0;
                x = __builtin_elementwise_max(x, z);
                #pragma unroll
                for (int n = 0; n < 8; ++n)
                    acc[t][n] = __builtin_amdgcn_mfma_f32_16x16x32_f16(x, b[n], acc[t][n], 0, 0, 0);
            }
        }
    }

    _Float16* epi = (_Float16*)(smem + 36864);         // 16 s x 16 d x 64 j = 32 KB
    int cn = lane & 15, rhi = (lane >> 4) * 4;
    for (int half = 0; half < 2; ++half) {
        __syncthreads();
        #pragma unroll
        for (int t = 0; t < 4; ++t) {
            int dl = wv*4 + t;
            #pragma unroll
            for (int n = 0; n < 4; ++n) {
                int j = n*16 + cn;
                float4v v = acc[t][half*4 + n];
                #pragma unroll
                for (int r = 0; r < 4; ++r)
                    epi[((rhi + r)*16 + dl)*64 + j] = (_Float16)v[r];
            }
        }
        __syncthreads();
        int srow = tid >> 4, dl = tid & 15;
        const uint4* src = (const uint4*)(epi + tid*64);
        uint4* dst = (uint4*)(TT + ((size_t)((g*16 + srow)*384 + d0 + dl))*64 + half*32);
        #pragma unroll
        for (int q = 0; q < 8; ++q) dst[q] = src[q];
    }
}

// ---------------- attention ----------------
__global__ void k_att(const uint32_t* __restrict__ TT, const float* __restrict__ R,
                      const float* __restrict__ w2, const float* __restrict__ b2,
                      int off, float* __restrict__ ATT) {
    int p = blockIdx.x * 256 + threadIdx.x;            // < 147456
    int s = p / 384, d = p - s * 384;
    __shared__ float w2s[64];
    if (threadIdx.x < 64) w2s[threadIdx.x] = w2[threadIdx.x];
    __syncthreads();
    const uint4* tp = (const uint4*)(TT + (size_t)p*64 + off);
    const float* rp = R + s*64;
    float logit = b2[0];
    #pragma unroll
    for (int m = 0; m < 8; ++m) {
        uint4 tv = tp[m];
        uint32_t us[4] = {tv.x, tv.y, tv.z, tv.w};
        #pragma unroll
        for (int q = 0; q < 4; ++q) {
            U32H2 c; c.u = us[q];
            int j = m*8 + q*2;
            float h0 = fmaxf((float)c.f[0] + rp[j],   0.f);
            float h1 = fmaxf((float)c.f[1] + rp[j+1], 0.f);
            logit += h0*w2s[j] + h1*w2s[j+1];
        }
    }
    float a = 1.f / (1.f + __expf(-logit));
    ATT[p] = (s == d) ? 0.f : a;
}

// ---------------- agg[d][c] = sum_s ATT[s,d] * X[s][c]  (tiled, coalesced) ----------------
__global__ void __launch_bounds__(256)
k_agg(const float* __restrict__ ATT, const float* __restrict__ X,
      float* __restrict__ AGG) {
    int tid = threadIdx.x;
    int d0 = blockIdx.x * 16;
    __shared__ float att_s[16][17];
    float acc[16];
    #pragma unroll
    for (int dl = 0; dl < 16; ++dl) acc[dl] = 0.f;

    for (int s0 = 0; s0 < 384; s0 += 16) {
        __syncthreads();
        {
            int row = tid >> 4, col = tid & 15;
            att_s[row][col] = ATT[(s0 + row)*384 + d0 + col];
        }
        __syncthreads();
        #pragma unroll 4
        for (int ss = 0; ss < 16; ++ss) {
            float x = X[(s0 + ss)*256 + tid];
            #pragma unroll
            for (int dl = 0; dl < 16; ++dl) acc[dl] += att_s[ss][dl] * x;
        }
    }
    #pragma unroll
    for (int dl = 0; dl < 16; ++dl)
        AGG[(d0 + dl)*256 + tid] = acc[dl];
}

__global__ void k_x0r1(const float* __restrict__ AGG, const float* __restrict__ W,
                       const float* __restrict__ b, const float* __restrict__ a1W1,
                       const float* __restrict__ a1b1, const float* __restrict__ cc,
                       float* __restrict__ X0, float* __restrict__ R1) {
    int d = blockIdx.x, tid = threadIdx.x;
    __shared__ float ag[256];
    __shared__ float xs[256];
    ag[tid] = AGG[d*256 + tid];
    __syncthreads();
    float acc = b[tid];
    for (int i = 0; i < 256; ++i) acc += ag[i] * W[i*256 + tid];
    acc = fmaxf(acc, 0.f);
    X0[d*256 + tid] = acc;
    xs[tid] = acc;
    __syncthreads();
    if (tid < 64) {
        float r = a1b1[tid] + cc[64 + tid];
        for (int i = 0; i < 256; ++i) r += xs[i] * a1W1[(128+i)*64 + tid];
        R1[d*64 + tid] = r;
    }
}

__global__ void k_colsum(const float* __restrict__ ATT, float* __restrict__ CS) {
    int s = blockIdx.x, t = threadIdx.x;               // block 64
    float acc = 0.f;
    for (int d = t; d < 384; d += 64) acc += ATT[s*384 + d];
    for (int o = 32; o > 0; o >>= 1) acc += __shfl_down(acc, o, 64);
    if (t == 0) CS[s] = acc;
}

__global__ void k_v(const float* __restrict__ CS, const float* __restrict__ X0,
                    float* __restrict__ V) {
    int tid = threadIdx.x;
    __shared__ float cs[384];
    for (int q = tid; q < 384; q += 256) cs[q] = CS[q];
    __syncthreads();
    float acc = 0.f;
    for (int s = 0; s < 384; s += 4) {
        acc += cs[s]*X0[s*256 + tid] + cs[s+1]*X0[(s+1)*256 + tid]
             + cs[s+2]*X0[(s+2)*256 + tid] + cs[s+3]*X0[(s+3)*256 + tid];
    }
    V[tid] = acc;
}

__global__ void k_out(const float* __restrict__ V, const float* __restrict__ W,
                      const float* __restrict__ b, float* __restrict__ out) {
    int tid = threadIdx.x;
    __shared__ float vs[256];
    vs[tid] = V[tid];
    __syncthreads();
    float acc = 384.f * b[tid];
    for (int i = 0; i < 256; ++i) acc += vs[i] * W[i*256 + tid];
    out[tid] = acc;
}

extern "C" void kernel_launch(void* const* d_in, const int* in_sizes, int n_in,
                              void* d_out, int out_size, void* d_ws, size_t ws_size,
                              hipStream_t stream) {
    if (ws_size < WS_TOTAL * sizeof(uint32_t)) return;

    const float* z    = (const float*)d_in[0];
    const float* Wih  = (const float*)d_in[1];
    const float* Whh  = (const float*)d_in[2];
    const float* bih  = (const float*)d_in[3];
    const float* bhh  = (const float*)d_in[4];
    const float* egW1 = (const float*)d_in[5];
    const float* egb1 = (const float*)d_in[6];
    const float* egW2 = (const float*)d_in[7];
    const float* egb2 = (const float*)d_in[8];
    const float* a0W1 = (const float*)d_in[9];
    const float* a0b1 = (const float*)d_in[10];
    const float* a0W2 = (const float*)d_in[11];
    const float* a0b2 = (const float*)d_in[12];
    const float* a1W1 = (const float*)d_in[13];
    const float* a1b1 = (const float*)d_in[14];
    const float* a1W2 = (const float*)d_in[15];
    const float* a1b2 = (const float*)d_in[16];
    const float* c0W  = (const float*)d_in[17];
    const float* c0b  = (const float*)d_in[18];
    const float* c1W  = (const float*)d_in[19];
    const float* c1b  = (const float*)d_in[20];

    uint32_t* ws   = (uint32_t*)d_ws;
    uint32_t* WL   = ws + OFF_W16T;
    float*    gi   = (float*)(ws + OFF_GI);
    float*    cc   = (float*)(ws + OFF_CC);
    uint32_t* BF   = ws + OFF_BF;
    float*    nodes= (float*)(ws + OFF_NODES);
    uint32_t* PF   = ws + OFF_PF;
    uint32_t* QF   = ws + OFF_QF;
    float*    R0   = (float*)(ws + OFF_R0);
    float*    R1   = (float*)(ws + OFF_R1);
    uint32_t* TT   = ws + OFF_TT;
    float*    ATT0 = (float*)(ws + OFF_ATT0);
    float*    ATT1 = (float*)(ws + OFF_ATT1);
    float*    AGG  = (float*)(ws + OFF_AGG);
    float*    X0   = (float*)(ws + OFF_X0);
    float*    CS   = (float*)(ws + OFF_CS);
    float*    V    = (float*)(ws + OFF_V);
    float*    out  = (float*)d_out;

    hipLaunchKernelGGL(k_prep_w16,    dim3(96),  dim3(256), 0, stream, Whh, WL);
    hipLaunchKernelGGL(k_prep_gi,     dim3(3),   dim3(256), 0, stream, z, Wih, bih, bhh, gi);
    hipLaunchKernelGGL(k_prep_cc,     dim3(1),   dim3(128), 0, stream, egb2, a0W1, a1W1, cc);
    hipLaunchKernelGGL(k_prep_w2a,    dim3(256), dim3(256), 0, stream, egW2, a0W1, a1W1, BF);
    hipLaunchKernelGGL(k_gru,         dim3(1),   dim3(512), 0, stream, gi, bhh, WL, nodes);
    hipLaunchKernelGGL(k_pq,          dim3(96),  dim3(256), 0, stream, nodes, egW1, egb1, a0W1, a0b1, cc, PF, QF, R0);
    hipLaunchKernelGGL(k_phaseA_mfma, dim3(24, 24), dim3(256), 0, stream, PF, QF, BF, TT);
    hipLaunchKernelGGL(k_att,         dim3(576), dim3(256), 0, stream, TT, R0, a0W2, a0b2, 0,  ATT0);
    hipLaunchKernelGGL(k_agg,         dim3(24),  dim3(256), 0, stream, ATT0, nodes, AGG);
    hipLaunchKernelGGL(k_x0r1,        dim3(384), dim3(256), 0, stream, AGG, c0W, c0b, a1W1, a1b1, cc, X0, R1);
    hipLaunchKernelGGL(k_att,         dim3(576), dim3(256), 0, stream, TT, R1, a1W2, a1b2, 32, ATT1);
    hipLaunchKernelGGL(k_colsum,      dim3(384), dim3(64),  0, stream, ATT1, CS);
    hipLaunchKernelGGL(k_v,           dim3(1),   dim3(256), 0, stream, CS, X0, V);
    hipLaunchKernelGGL(k_out,         dim3(1),   dim3(256), 0, stream, V, c1W, c1b, out);
}

// Round 2
// 699.481 us; speedup vs baseline: 1.1403x; 1.0076x over previous
//
#include <hip/hip_runtime.h>
#include <hip/hip_fp16.h>
#include <cstdint>

#define DEV static __device__ __forceinline__

typedef _Float16 h2v __attribute__((ext_vector_type(2)));
typedef _Float16 half8 __attribute__((ext_vector_type(8)));
typedef float float4v __attribute__((ext_vector_type(4)));

union U32H2 { uint32_t u; _Float16 f[2]; };

DEV uint32_t pack_f2(float a, float b) {
    auto p = __builtin_amdgcn_cvt_pkrtz(a, b);
    return __builtin_bit_cast(uint32_t, p);
}

DEV half8 bc8(uint4 v) { return __builtin_bit_cast(half8, v); }

DEV float sigmoidf_(float x) { return 1.0f / (1.0f + __expf(-x)); }

DEV void gl_lds16(const void* gsrc, void* ldst) {
    __builtin_amdgcn_global_load_lds(
        (const __attribute__((address_space(1))) uint32_t*)gsrc,
        (__attribute__((address_space(3))) uint32_t*)ldst, 16, 0, 0);
}

// select element r (0..3) of (bsel ? hi : lo) with compile-time-constant indices only
DEV float pick4(float4v lo, float4v hi, int bsel, int r) {
    float v0 = bsel ? hi[0] : lo[0];
    float v1 = bsel ? hi[1] : lo[1];
    float v2 = bsel ? hi[2] : lo[2];
    float v3 = bsel ? hi[3] : lo[3];
    float x01 = (r & 1) ? v1 : v0;
    float x23 = (r & 1) ? v3 : v2;
    return (r & 2) ? x23 : x01;
}

// ---------------- workspace layout (uint32 units) ----------------
// N=384 H=256 Z=128 ED=128 AH=64
static const size_t OFF_W16T  = 0;          // 98304  : Whh f16 as MFMA A-fragments (k_gru layout)
static const size_t OFF_GI    = 98304;      // 768    : gsum = gi + bhh (r,z thirds), gi only (n third)
static const size_t OFF_CC    = 99072;      // 128
static const size_t OFF_BF    = 99200;      // 65536  : W2A in MFMA B-frag layout
static const size_t OFF_NODES = 164736;     // 98304  : GRU outputs fp32 [384][256]
static const size_t OFF_PF    = 263040;     // 196608 : P in MFMA A-frag layout
static const size_t OFF_QF    = 459648;     // 196608 : Q natural f16 [384][512 u32]
static const size_t OFF_R0    = 656256;     // 24576
static const size_t OFF_R1    = 680832;     // 24576
static const size_t OFF_TT    = 705408;     // 9437184: T f16 [s][d][64 u32]
static const size_t OFF_ATT0  = 10142592;   // 147456
static const size_t OFF_ATT1  = 10290048;   // 147456
static const size_t OFF_AGG   = 10437504;   // 98304
static const size_t OFF_X0    = 10535808;   // 98304
static const size_t OFF_CS    = 10634112;   // 384
static const size_t OFF_V     = 10634496;   // 256
static const size_t WS_TOTAL  = 10634752;   // u32 elems (~42.5 MB)

// ---------------- fused prep kernel ----------------
// blocks [0,96): WL (Whh -> MFMA A-frags, gate-local rows)
// blocks [96,99): gs
// block  99     : cc
// blocks [100,356): BF (W2A in MFMA B-frag layout)
__global__ void k_prep_all(const float* __restrict__ Whh, uint32_t* __restrict__ WL,
                           const float* __restrict__ z, const float* __restrict__ Wih,
                           const float* __restrict__ bih, const float* __restrict__ bhh,
                           float* __restrict__ gs,
                           const float* __restrict__ egb2, const float* __restrict__ a0W1,
                           const float* __restrict__ a1W1, float* __restrict__ cc,
                           const float* __restrict__ egW2, uint32_t* __restrict__ BF) {
    int bb = blockIdx.x;
    if (bb < 96) {
        // WL: wave wv owns h-elements [wv*32, wv*32+32); tile rt: gate rt>>1,
        // row = (rt>>1)*256 + wv*32 + ((rt&1)<<4) + (lane&15)
        int o4 = bb * 256 + threadIdx.x;               // < 24576
        int c = o4 >> 9, t = o4 & 511;
        int rt = c >> 3, kt = c & 7;
        int lane = t & 63, wv = t >> 6;
        int row = (rt >> 1) * 256 + wv * 32 + ((rt & 1) << 4) + (lane & 15);
        int k0 = kt*32 + (lane >> 4)*8;
        const float* src = Whh + row*256 + k0;
        uint4 o;
        o.x = pack_f2(src[0], src[1]);
        o.y = pack_f2(src[2], src[3]);
        o.z = pack_f2(src[4], src[5]);
        o.w = pack_f2(src[6], src[7]);
        ((uint4*)WL)[o4] = o;
    } else if (bb < 99) {
        int o = (bb - 96) * 256 + threadIdx.x;         // < 768
        float acc = bih[o];
        if (o < 512) acc += bhh[o];
        for (int i = 0; i < 128; ++i) acc += Wih[o*128 + i] * z[i];
        gs[o] = acc;
    } else if (bb == 99) {
        int t = threadIdx.x;
        if (t < 128) {
            const float* A = (t < 64) ? a0W1 : a1W1;
            int j = t & 63;
            float acc = 0.f;
            for (int i = 0; i < 128; ++i) acc += egb2[i] * A[i*64 + j];
            cc[t] = acc;
        }
    } else {
        int idx = (bb - 100) * 256 + threadIdx.x;      // < 65536
        int k2 = idx >> 7, n = idx & 127;
        const float* A = (n < 64) ? (a0W1 + n) : (a1W1 + (n - 64));
        const float* w0 = egW2 + (2*k2) * 128;
        float a = 0.f, b = 0.f;
        for (int i = 0; i < 128; ++i) {
            float av = A[i*64];
            a += w0[i] * av;
            b += w0[128 + i] * av;
        }
        int kk = k2 >> 4, jgrp = (k2 >> 2) & 3, sub = k2 & 3;
        int lane = jgrp*16 + (n & 15), t = n >> 4;
        BF[((kk*8 + t)*64 + lane)*4 + sub] = pack_f2(a, b);
    }
}

// ---------------- GRU: 512 threads; Whh in AGPRs as MFMA A-operands ----------------
// v4: phase-split MFMA issue. r-gate chains (d0,d1) complete first so the rg
// sigmoid overlaps the z/n-gate MFMAs; serial tail is only the n-gate chain.
// One raw s_barrier per step; h double-buffered in LDS; nodes store undrained.
__global__ void __launch_bounds__(512, 2)
k_gru(const float* __restrict__ gs, const float* __restrict__ bhh,
      const uint32_t* __restrict__ WL, float* __restrict__ nodes) {
    int tid = threadIdx.x;
    int lane = tid & 63, wv = tid >> 6;
    int kq = lane >> 4, c = lane & 15;
    __shared__ __align__(16) _Float16 hh16[512];       // 2 buffers x 256 f16

    // load 48 A-frags, pin each 32-bit component to the AGPR class
    uint4 w[48];
    const uint4* wl4 = (const uint4*)WL;
    #pragma unroll
    for (int cc = 0; cc < 48; ++cc) w[cc] = wl4[cc*512 + tid];
    #pragma unroll
    for (int cc = 0; cc < 48; ++cc)
        asm volatile("" : "+a"(w[cc].x), "+a"(w[cc].y), "+a"(w[cc].z), "+a"(w[cc].w));

    const float L2E = 1.44269504088896f;
    int r = c & 3, bsel = (c >> 2) & 1;                // c>=8 duplicates c-8; inactive
    int i_loc = kq*4 + r + bsel*16;
    int gidx = wv*32 + i_loc;
    float pr = -L2E * gs[gidx];
    float pz = -L2E * gs[256 + gidx];
    float gin_l = gs[512 + gidx];
    float bn_l  = bhh[512 + gidx];
    float pn = -2.f * L2E * gin_l;
    bool active = (c < 8);

    float h = 0.f;
    if (tid < 256) ((uint32_t*)hh16)[tid] = 0u;        // zero both buffers
    __syncthreads();

    const float4v z4 = {0.f, 0.f, 0.f, 0.f};
    int par = 0;
    for (int t = 0; t < 384; ++t) {
        const _Float16* hb = hh16 + par*256 + kq*8;
        uint4 b[8];
        #pragma unroll
        for (int kt = 0; kt < 8; ++kt) b[kt] = *(const uint4*)(hb + kt*32);

        // phase 1: r-gate tiles d0,d1 — finish first
        float4v d0, d1, d2, d3, d4, d5;
        d0 = __builtin_amdgcn_mfma_f32_16x16x32_f16(bc8(w[0]),  bc8(b[0]), z4, 0, 0, 0);
        d1 = __builtin_amdgcn_mfma_f32_16x16x32_f16(bc8(w[8]),  bc8(b[0]), z4, 0, 0, 0);
        #pragma unroll
        for (int kt = 1; kt < 8; ++kt) {
            d0 = __builtin_amdgcn_mfma_f32_16x16x32_f16(bc8(w[kt]),    bc8(b[kt]), d0, 0, 0, 0);
            d1 = __builtin_amdgcn_mfma_f32_16x16x32_f16(bc8(w[8+kt]),  bc8(b[kt]), d1, 0, 0, 0);
        }
        // rg sigmoid overlaps phase 2 MFMAs below
        float ghr = pick4(d0, d1, bsel, r);
        float er = __builtin_amdgcn_exp2f(__builtin_fmaf(ghr, -L2E, pr));
        float rg = __builtin_amdgcn_rcpf(1.f + er);

        // phase 2: z + n tiles (4 independent chains)
        d2 = __builtin_amdgcn_mfma_f32_16x16x32_f16(bc8(w[16]), bc8(b[0]), z4, 0, 0, 0);
        d3 = __builtin_amdgcn_mfma_f32_16x16x32_f16(bc8(w[24]), bc8(b[0]), z4, 0, 0, 0);
        d4 = __builtin_amdgcn_mfma_f32_16x16x32_f16(bc8(w[32]), bc8(b[0]), z4, 0, 0, 0);
        d5 = __builtin_amdgcn_mfma_f32_16x16x32_f16(bc8(w[40]), bc8(b[0]), z4, 0, 0, 0);
        #pragma unroll
        for (int kt = 1; kt < 8; ++kt) {
            d2 = __builtin_amdgcn_mfma_f32_16x16x32_f16(bc8(w[16+kt]), bc8(b[kt]), d2, 0, 0, 0);
            d3 = __builtin_amdgcn_mfma_f32_16x16x32_f16(bc8(w[24+kt]), bc8(b[kt]), d3, 0, 0, 0);
            d4 = __builtin_amdgcn_mfma_f32_16x16x32_f16(bc8(w[32+kt]), bc8(b[kt]), d4, 0, 0, 0);
            d5 = __builtin_amdgcn_mfma_f32_16x16x32_f16(bc8(w[40+kt]), bc8(b[kt]), d5, 0, 0, 0);
        }

        float ghz = pick4(d2, d3, bsel, r);
        float ghn = pick4(d4, d5, bsel, r);
        float eu = __builtin_amdgcn_exp2f(__builtin_fmaf(ghz, -L2E, pz));
        float u  = __builtin_amdgcn_rcpf(1.f + eu);
        float tm = ghn + bn_l;
        float q  = __builtin_fmaf(rg * tm, -2.f * L2E, pn);
        float e2 = __builtin_amdgcn_exp2f(q);
        float nn = __builtin_fmaf(2.f, __builtin_amdgcn_rcpf(1.f + e2), -1.f);
        h = nn + u * (h - nn);

        if (active) {
            hh16[(par ^ 1)*256 + gidx] = (_Float16)h;
            nodes[t*256 + gidx] = h;                   // HBM store: not drained at barrier
        }
        asm volatile("s_waitcnt lgkmcnt(0)" ::: "memory");
        __builtin_amdgcn_sched_barrier(0);
        __builtin_amdgcn_s_barrier();
        __builtin_amdgcn_sched_barrier(0);
        par ^= 1;
    }
}

// ---------------- P (A-frag layout), Q (natural f16), R0 ----------------
__global__ void k_pq(const float* __restrict__ nodes, const float* __restrict__ eg_W1,
                     const float* __restrict__ eg_b1, const float* __restrict__ a0W1,
                     const float* __restrict__ a0b1, const float* __restrict__ cc,
                     uint32_t* __restrict__ PF, uint32_t* __restrict__ QF,
                     float* __restrict__ R0) {
    int tid = threadIdx.x;
    int s0 = blockIdx.x * 4;
    __shared__ float ns[4][256];
    #pragma unroll
    for (int q = 0; q < 4; ++q) ns[q][tid] = nodes[(s0+q)*256 + tid];
    __syncthreads();

    int k0 = tid * 4;
    float acc[4][4];
    #pragma unroll
    for (int q = 0; q < 4; ++q) { acc[q][0]=0;acc[q][1]=0;acc[q][2]=0;acc[q][3]=0; }
    for (int i = 0; i < 256; ++i) {
        float4 wv = *(const float4*)&eg_W1[i*1024 + k0];
        #pragma unroll
        for (int q = 0; q < 4; ++q) {
            float nv = ns[q][i];
            acc[q][0] += nv*wv.x; acc[q][1] += nv*wv.y;
            acc[q][2] += nv*wv.z; acc[q][3] += nv*wv.w;
        }
    }
    float4 bv = *(const float4*)&eg_b1[k0];
    {
        int kk = k0 >> 5;
        int lgrp = ((k0 >> 3) & 3) * 16;
        int sub = (k0 & 7) >> 1;                       // 0 or 2
        #pragma unroll
        for (int q = 0; q < 4; ++q) {
            int s = s0 + q, g = s >> 4, srow = s & 15;
            uint2 pw;
            pw.x = pack_f2(acc[q][0] + bv.x, acc[q][1] + bv.y);
            pw.y = pack_f2(acc[q][2] + bv.z, acc[q][3] + bv.w);
            *(uint2*)(PF + (((g*32 + kk)*64 + lgrp + srow) << 2) + sub) = pw;
        }
    }

    #pragma unroll
    for (int q = 0; q < 4; ++q) { acc[q][0]=0;acc[q][1]=0;acc[q][2]=0;acc[q][3]=0; }
    for (int i = 0; i < 256; ++i) {
        float4 wv = *(const float4*)&eg_W1[(256+i)*1024 + k0];
        #pragma unroll
        for (int q = 0; q < 4; ++q) {
            float nv = ns[q][i];
            acc[q][0] += nv*wv.x; acc[q][1] += nv*wv.y;
            acc[q][2] += nv*wv.z; acc[q][3] += nv*wv.w;
        }
    }
    #pragma unroll
    for (int q = 0; q < 4; ++q) {
        uint2 pw;
        pw.x = pack_f2(acc[q][0], acc[q][1]);
        pw.y = pack_f2(acc[q][2], acc[q][3]);
        ((uint2*)QF)[(s0+q)*256 + tid] = pw;           // QF[d][k/2], natural order
    }

    int srow = tid >> 6, j = tid & 63;
    float racc = a0b1[j] + cc[j];
    for (int i = 0; i < 256; ++i) racc += ns[srow][i] * a0W1[(128+i)*64 + j];
    R0[(s0+srow)*64 + j] = racc;
}

// ---------------- phase A (MFMA): T[s,d,:] = relu(P[s]+Q[d]) @ W2A ----------------
// v2: 16 half-chunks (2 kk each), double-buffered P/B staging: loads for hc+1
// fly while computing hc; vmcnt(0) after compute, one barrier per half-chunk.
DEV void stageA(const uint32_t* __restrict__ PF, const uint32_t* __restrict__ BF,
                int g, int hc, char* buf, int tid) {
    const char* psrc = (const char*)(PF + ((size_t)g*32 + (size_t)hc*2) * 256);
    if (tid < 128) gl_lds16(psrc + tid*16, buf + tid*16);
    const char* bsrc = (const char*)(BF + (size_t)hc * 4096);
    #pragma unroll
    for (int i = 0; i < 4; ++i)
        gl_lds16(bsrc + tid*16 + i*4096, buf + 2048 + tid*16 + i*4096);
}

__global__ void __launch_bounds__(256, 2)
k_phaseA_mfma(const uint32_t* __restrict__ PF, const uint32_t* __restrict__ QF,
              const uint32_t* __restrict__ BF, uint32_t* __restrict__ TT) {
    __shared__ __align__(16) char smem[69632];
    uint4* Qs4 = (uint4*)smem;                         // 16 d x 128 uint4 = 32 KB
    char* bufbase = smem + 32768;                      // 2 x (2KB P + 16KB B) = 36 KB

    int tid = threadIdx.x;
    int lane = tid & 63, wv = tid >> 6;
    int g = blockIdx.x, d0 = blockIdx.y * 16;

    {
        const char* src = (const char*)(QF + (size_t)d0 * 512);
        int off = tid * 16;
        #pragma unroll
        for (int i = 0; i < 8; ++i)
            gl_lds16(src + off + i*4096, (char*)Qs4 + off + i*4096);
    }
    stageA(PF, BF, g, 0, bufbase, tid);
    asm volatile("s_waitcnt vmcnt(0)" ::: "memory");
    __builtin_amdgcn_sched_barrier(0);
    __builtin_amdgcn_s_barrier();
    __builtin_amdgcn_sched_barrier(0);

    float4v acc[4][8];
    #pragma unroll
    for (int t = 0; t < 4; ++t)
        #pragma unroll
        for (int n = 0; n < 8; ++n) acc[t][n] = 0.f;

    for (int hc = 0; hc < 16; ++hc) {
        char* cur = bufbase + (hc & 1) * 18432;
        char* nxt = bufbase + ((hc + 1) & 1) * 18432;
        if (hc < 15) stageA(PF, BF, g, hc + 1, nxt, tid);

        uint4* Ph = (uint4*)cur;                       // [2 kk][64 lane]
        uint4* Bh = (uint4*)(cur + 2048);              // [2 kk][8 t][64 lane]
        #pragma unroll
        for (int kkl = 0; kkl < 2; ++kkl) {
            int kkg = hc*2 + kkl;
            half8 b[8];
            #pragma unroll
            for (int n = 0; n < 8; ++n) b[n] = bc8(Bh[(kkl*8 + n)*64 + lane]);
            half8 p8 = bc8(Ph[kkl*64 + lane]);
            #pragma unroll
            for (int t = 0; t < 4; ++t) {
                half8 q8 = bc8(Qs4[(wv*4 + t)*128 + kkg*4 + (lane >> 4)]);
                half8 x = p8 + q8;
                half8 zz = 0;
                x = __builtin_elementwise_max(x, zz);
                #pragma unroll
                for (int n = 0; n < 8; ++n)
                    acc[t][n] = __builtin_amdgcn_mfma_f32_16x16x32_f16(x, b[n], acc[t][n], 0, 0, 0);
            }
        }
        asm volatile("s_waitcnt vmcnt(0)" ::: "memory");
        __builtin_amdgcn_sched_barrier(0);
        __builtin_amdgcn_s_barrier();
        __builtin_amdgcn_sched_barrier(0);
    }

    _Float16* epi = (_Float16*)(smem + 32768);         // 16 s x 16 d x 64 j = 32 KB
    int cn = lane & 15, rhi = (lane >> 4) * 4;
    for (int half = 0; half < 2; ++half) {
        __syncthreads();
        #pragma unroll
        for (int t = 0; t < 4; ++t) {
            int dl = wv*4 + t;
            #pragma unroll
            for (int n = 0; n < 4; ++n) {
                int j = n*16 + cn;
                float4v v = acc[t][half*4 + n];
                #pragma unroll
                for (int r = 0; r < 4; ++r)
                    epi[((rhi + r)*16 + dl)*64 + j] = (_Float16)v[r];
            }
        }
        __syncthreads();
        int srow = tid >> 4, dl = tid & 15;
        const uint4* src = (const uint4*)(epi + tid*64);
        uint4* dst = (uint4*)(TT + ((size_t)((g*16 + srow)*384 + d0 + dl))*64 + half*32);
        #pragma unroll
        for (int q = 0; q < 8; ++q) dst[q] = src[q];
    }
}

// ---------------- attention (+optional fused column-sum) ----------------
__global__ void k_att(const uint32_t* __restrict__ TT, const float* __restrict__ R,
                      const float* __restrict__ w2, const float* __restrict__ b2,
                      int off, float* __restrict__ ATT, float* __restrict__ CS) {
    int tid = threadIdx.x;
    int p = blockIdx.x * 256 + tid;                    // < 147456
    int s = p / 384, d = p - s * 384;
    int sa = (blockIdx.x * 256) / 384;                 // block spans s in {sa, sa+1}
    __shared__ float w2s[64];
    __shared__ float rs[2][64];
    if (tid < 64) w2s[tid] = w2[tid];
    else if (tid < 128) rs[0][tid - 64] = R[sa*64 + (tid - 64)];
    else if (tid < 192) {
        int sb = sa + 1;
        rs[1][tid - 128] = (sb < 384) ? R[sb*64 + (tid - 128)] : 0.f;
    }
    __syncthreads();
    const uint4* tp = (const uint4*)(TT + (size_t)p*64 + off);
    const float* rp = (s == sa) ? rs[0] : rs[1];
    float logit = b2[0];
    #pragma unroll
    for (int m = 0; m < 8; ++m) {
        uint4 tv = tp[m];
        uint32_t us[4] = {tv.x, tv.y, tv.z, tv.w};
        #pragma unroll
        for (int q = 0; q < 4; ++q) {
            U32H2 c; c.u = us[q];
            int j = m*8 + q*2;
            float h0 = fmaxf((float)c.f[0] + rp[j],   0.f);
            float h1 = fmaxf((float)c.f[1] + rp[j+1], 0.f);
            logit += h0*w2s[j] + h1*w2s[j+1];
        }
    }
    float a = 1.f / (1.f + __expf(-logit));
    float a_eff = (s == d) ? 0.f : a;
    ATT[p] = a_eff;

    if (CS) {
        float va = (s == sa) ? a_eff : 0.f;
        float vb = (s != sa) ? a_eff : 0.f;
        #pragma unroll
        for (int o = 32; o > 0; o >>= 1) {
            va += __shfl_down(va, o, 64);
            vb += __shfl_down(vb, o, 64);
        }
        if ((tid & 63) == 0) {
            atomicAdd(&CS[sa], va);
            int sb = sa + 1;
            if (sb < 384) atomicAdd(&CS[sb], vb);
        }
    }
}

// ---------------- agg[d][c] = sum_s ATT[s,d] * X[s][c]  (tiled, coalesced) ----------------
__global__ void __launch_bounds__(256)
k_agg(const float* __restrict__ ATT, const float* __restrict__ X,
      float* __restrict__ AGG) {
    int tid = threadIdx.x;
    int d0 = blockIdx.x * 16;
    __shared__ float att_s[16][17];
    float acc[16];
    #pragma unroll
    for (int dl = 0; dl < 16; ++dl) acc[dl] = 0.f;

    for (int s0 = 0; s0 < 384; s0 += 16) {
        __syncthreads();
        {
            int row = tid >> 4, col = tid & 15;
            att_s[row][col] = ATT[(s0 + row)*384 + d0 + col];
        }
        __syncthreads();
        #pragma unroll 4
        for (int ss = 0; ss < 16; ++ss) {
            float x = X[(s0 + ss)*256 + tid];
            #pragma unroll
            for (int dl = 0; dl < 16; ++dl) acc[dl] += att_s[ss][dl] * x;
        }
    }
    #pragma unroll
    for (int dl = 0; dl < 16; ++dl)
        AGG[(d0 + dl)*256 + tid] = acc[dl];
}

__global__ void k_x0r1(const float* __restrict__ AGG, const float* __restrict__ W,
                       const float* __restrict__ b, const float* __restrict__ a1W1,
                       const float* __restrict__ a1b1, const float* __restrict__ cc,
                       float* __restrict__ X0, float* __restrict__ R1) {
    int d = blockIdx.x, tid = threadIdx.x;
    __shared__ float ag[256];
    __shared__ float xs[256];
    ag[tid] = AGG[d*256 + tid];
    __syncthreads();
    float acc = b[tid];
    for (int i = 0; i < 256; ++i) acc += ag[i] * W[i*256 + tid];
    acc = fmaxf(acc, 0.f);
    X0[d*256 + tid] = acc;
    xs[tid] = acc;
    __syncthreads();
    if (tid < 64) {
        float r = a1b1[tid] + cc[64 + tid];
        for (int i = 0; i < 256; ++i) r += xs[i] * a1W1[(128+i)*64 + tid];
        R1[d*64 + tid] = r;
    }
}

// ---------------- fused V + out (single block) ----------------
__global__ void k_vout(const float* __restrict__ CS, const float* __restrict__ X0,
                       const float* __restrict__ W, const float* __restrict__ b,
                       float* __restrict__ out) {
    int tid = threadIdx.x;
    __shared__ float cs[384];
    __shared__ float vs[256];
    for (int q = tid; q < 384; q += 256) cs[q] = CS[q];
    __syncthreads();
    float acc = 0.f;
    for (int s = 0; s < 384; s += 4) {
        acc += cs[s]*X0[s*256 + tid] + cs[s+1]*X0[(s+1)*256 + tid]
             + cs[s+2]*X0[(s+2)*256 + tid] + cs[s+3]*X0[(s+3)*256 + tid];
    }
    vs[tid] = acc;
    __syncthreads();
    float o = 384.f * b[tid];
    for (int i = 0; i < 256; ++i) o += vs[i] * W[i*256 + tid];
    out[tid] = o;
}

extern "C" void kernel_launch(void* const* d_in, const int* in_sizes, int n_in,
                              void* d_out, int out_size, void* d_ws, size_t ws_size,
                              hipStream_t stream) {
    if (ws_size < WS_TOTAL * sizeof(uint32_t)) return;

    const float* z    = (const float*)d_in[0];
    const float* Wih  = (const float*)d_in[1];
    const float* Whh  = (const float*)d_in[2];
    const float* bih  = (const float*)d_in[3];
    const float* bhh  = (const float*)d_in[4];
    const float* egW1 = (const float*)d_in[5];
    const float* egb1 = (const float*)d_in[6];
    const float* egW2 = (const float*)d_in[7];
    const float* egb2 = (const float*)d_in[8];
    const float* a0W1 = (const float*)d_in[9];
    const float* a0b1 = (const float*)d_in[10];
    const float* a0W2 = (const float*)d_in[11];
    const float* a0b2 = (const float*)d_in[12];
    const float* a1W1 = (const float*)d_in[13];
    const float* a1b1 = (const float*)d_in[14];
    const float* a1W2 = (const float*)d_in[15];
    const float* a1b2 = (const float*)d_in[16];
    const float* c0W  = (const float*)d_in[17];
    const float* c0b  = (const float*)d_in[18];
    const float* c1W  = (const float*)d_in[19];
    const float* c1b  = (const float*)d_in[20];

    uint32_t* ws   = (uint32_t*)d_ws;
    uint32_t* WL   = ws + OFF_W16T;
    float*    gi   = (float*)(ws + OFF_GI);
    float*    cc   = (float*)(ws + OFF_CC);
    uint32_t* BF   = ws + OFF_BF;
    float*    nodes= (float*)(ws + OFF_NODES);
    uint32_t* PF   = ws + OFF_PF;
    uint32_t* QF   = ws + OFF_QF;
    float*    R0   = (float*)(ws + OFF_R0);
    float*    R1   = (float*)(ws + OFF_R1);
    uint32_t* TT   = ws + OFF_TT;
    float*    ATT0 = (float*)(ws + OFF_ATT0);
    float*    ATT1 = (float*)(ws + OFF_ATT1);
    float*    AGG  = (float*)(ws + OFF_AGG);
    float*    X0   = (float*)(ws + OFF_X0);
    float*    CS   = (float*)(ws + OFF_CS);
    float*    out  = (float*)d_out;

    hipMemsetAsync(CS, 0, 384 * sizeof(float), stream);
    hipLaunchKernelGGL(k_prep_all,    dim3(356), dim3(256), 0, stream,
                       Whh, WL, z, Wih, bih, bhh, gi, egb2, a0W1, a1W1, cc, egW2, BF);
    hipLaunchKernelGGL(k_gru,         dim3(1),   dim3(512), 0, stream, gi, bhh, WL, nodes);
    hipLaunchKernelGGL(k_pq,          dim3(96),  dim3(256), 0, stream, nodes, egW1, egb1, a0W1, a0b1, cc, PF, QF, R0);
    hipLaunchKernelGGL(k_phaseA_mfma, dim3(24, 24), dim3(256), 0, stream, PF, QF, BF, TT);
    hipLaunchKernelGGL(k_att,         dim3(576), dim3(256), 0, stream, TT, R0, a0W2, a0b2, 0,  ATT0, (float*)nullptr);
    hipLaunchKernelGGL(k_agg,         dim3(24),  dim3(256), 0, stream, ATT0, nodes, AGG);
    hipLaunchKernelGGL(k_x0r1,        dim3(384), dim3(256), 0, stream, AGG, c0W, c0b, a1W1, a1b1, cc, X0, R1);
    hipLaunchKernelGGL(k_att,         dim3(576), dim3(256), 0, stream, TT, R1, a1W2, a1b2, 32, ATT1, CS);
    hipLaunchKernelGGL(k_vout,        dim3(1),   dim3(256), 0, stream, CS, X0, c1W, c1b, out);
}